// Round 3
// baseline (8877.156 us; speedup 1.0000x reference)
//
#include <hip/hip_runtime.h>
#include <cmath>

// ---------------------------------------------------------------------------
// RQ-VAE forward, round 3.
// enc3/enc4: conv_mfma with 3-word bf16 split (6 products, split accumulator)
//   -> z error at fp32-reorder-noise level -> index-exact argmin.
// dec1/convT2/convT3: conv_mfma 2-word (3 products) — proven by round-2 recon.
// enc1/enc2, convT4 head: fp32 conv_tiled. VQ: fp32 fused GEMM+argmin.
//
// Workspace (floats), DA = 2097152, total 85,983,232 f = 344 MB:
//   [0, 2022400): wp2/wp3/wp4/cbn fp32 + bf16 weight planes
//   DA+0        : h1 / h3 / zt / d1 / D3
//   DA+16777216 : h2 / A4(3 planes) / res / d2 / d3
//   DA+25165824 : A3 (3 planes)
//   DA+33554432 : D1 (2 planes)
//   DA+41943040 : z
// ---------------------------------------------------------------------------

typedef unsigned short u16;
typedef unsigned int   u32;
typedef __attribute__((ext_vector_type(8))) short s16x8;
typedef __attribute__((ext_vector_type(4))) short s16x4;
typedef __attribute__((ext_vector_type(4))) float f32x4;
typedef __attribute__((address_space(1))) const u32 gu32;
typedef __attribute__((address_space(3))) u32 lu32;

__device__ __forceinline__ u16 f2bf(float v) {   // RNE fp32->bf16 bits
  u32 b = __builtin_bit_cast(u32, v);
  b += 0x7FFFu + ((b >> 16) & 1u);
  return (u16)(b >> 16);
}
__device__ __forceinline__ float bf2f(u16 h) {
  u32 b = ((u32)h) << 16;
  return __builtin_bit_cast(float, b);
}

// ---------------- row vector load from LDS (aligned) ----------------
template<int RW>
__device__ __forceinline__ void load_row(const float* __restrict__ p, float* r) {
  if constexpr (RW == 5) {
    float4 a = *(const float4*)p;
    r[0]=a.x; r[1]=a.y; r[2]=a.z; r[3]=a.w; r[4]=p[4];
  } else if constexpr (RW == 6) {
    float4 a = *(const float4*)p; float2 b = *(const float2*)(p+4);
    r[0]=a.x; r[1]=a.y; r[2]=a.z; r[3]=a.w; r[4]=b.x; r[5]=b.y;
  } else if constexpr (RW == 10) {
    float4 a = *(const float4*)p; float4 b = *(const float4*)(p+4);
    float2 c = *(const float2*)(p+8);
    r[0]=a.x; r[1]=a.y; r[2]=a.z; r[3]=a.w;
    r[4]=b.x; r[5]=b.y; r[6]=b.z; r[7]=b.w; r[8]=c.x; r[9]=c.y;
  }
}

// ---------------- generic tiled direct conv (fp32 light layers) ----------
template<int OCT, int SPTH, int SPTW, int KH, int KW, int S, int ACT>
__global__ __launch_bounds__(256) void conv_tiled(
    const float* __restrict__ in, const float* __restrict__ wgt,
    const float* __restrict__ bias, float* __restrict__ out,
    int N, int Cin, int Hin, int Win, int Cout, int WT,
    int padY, int padX,
    long outBase, long outNStride, long outCStride, long outYStride, long outXStride)
{
  constexpr int CK   = 8;
  constexpr int IH   = (SPTH-1)*S + KH;
  constexpr int IWr  = (SPTW-1)*S + KW;
  constexpr int IW   = (IWr + 3) & ~3;
  constexpr int TAPS = KH*KW;
  constexpr int WST  = (OCT==64) ? 68 : 5;
  constexpr int LOC  = (OCT==64) ? 16 : 4;
  constexpr int OPT  = OCT/LOC;
  constexpr int RW   = 3*S + KW;
  constexpr int EPW  = (OCT==64) ? 65 : 257;
  constexpr int SP   = SPTH*SPTW;
  constexpr int STG  = CK*IH*IW + CK*TAPS*WST;
  constexpr int SMEMN = (STG > OCT*EPW) ? STG : OCT*EPW;
  __shared__ float smem[SMEMN];
  float* s_in = smem;
  float* s_w  = smem + CK*IH*IW;

  const int tid  = threadIdx.x;
  const int tile = blockIdx.x, ocb = blockIdx.y, n = blockIdx.z;
  const int oy0 = (tile / WT) * SPTH, ox0 = (tile % WT) * SPTW;
  const int ol  = tid % LOC;
  const int g   = tid / LOC;
  const int s0  = g * 4;
  const int sy  = s0 / SPTW, sx0 = s0 % SPTW;
  const int iy0 = oy0*S - padY, ix0 = ox0*S - padX;

  float acc[OPT][4];
#pragma unroll
  for (int o = 0; o < OPT; ++o)
#pragma unroll
    for (int j = 0; j < 4; ++j) acc[o][j] = 0.f;

  for (int c0 = 0; c0 < Cin; c0 += CK) {
    __syncthreads();
    for (int i = tid; i < CK*IH*IW; i += 256) {
      int c = i / (IH*IW), r2 = i % (IH*IW);
      int iy = r2 / IW, ix = r2 % IW;
      int gy = iy0 + iy, gx = ix0 + ix;
      float v = 0.f;
      if (c0 + c < Cin && (unsigned)gy < (unsigned)Hin && (unsigned)gx < (unsigned)Win)
        v = in[(((long)n*Cin + c0 + c)*Hin + gy)*Win + gx];
      s_in[i] = v;
    }
    for (int i = tid; i < OCT*CK*TAPS; i += 256) {
      int o = i / (CK*TAPS), ct = i % (CK*TAPS);
      int oc = ocb*OCT + o, ci = c0 + ct / TAPS;
      float v = 0.f;
      if (oc < Cout && ci < Cin)
        v = wgt[((long)oc*Cin + ci)*TAPS + (ct % TAPS)];
      s_w[ct*WST + o] = v;
    }
    __syncthreads();

    for (int c = 0; c < CK; ++c) {
#pragma unroll
      for (int ky = 0; ky < KH; ++ky) {
        float r[RW];
        load_row<RW>(&s_in[c*(IH*IW) + (sy*S + ky)*IW + sx0*S], r);
#pragma unroll
        for (int kx = 0; kx < KW; ++kx) {
          if constexpr (OCT == 64) {
            float4 w4 = *(const float4*)&s_w[(c*TAPS + ky*KW + kx)*WST + ol*4];
            float wv[4] = {w4.x, w4.y, w4.z, w4.w};
#pragma unroll
            for (int o = 0; o < 4; ++o)
#pragma unroll
              for (int j = 0; j < 4; ++j)
                acc[o][j] = fmaf(wv[o], r[j*S + kx], acc[o][j]);
          } else {
            float w = s_w[(c*TAPS + ky*KW + kx)*WST + ol];
#pragma unroll
            for (int j = 0; j < 4; ++j)
              acc[0][j] = fmaf(w, r[j*S + kx], acc[0][j]);
          }
        }
      }
    }
  }

  __syncthreads();
#pragma unroll
  for (int o = 0; o < OPT; ++o) {
    int oc = ocb*OCT + ol*OPT + o;
    float b = (oc < Cout) ? bias[oc] : 0.f;
#pragma unroll
    for (int j = 0; j < 4; ++j) {
      float v = acc[o][j] + b;
      if constexpr (ACT == 1) v = fmaxf(v, 0.f);
      else if constexpr (ACT == 2) v = tanhf(v);
      smem[(ol*OPT + o)*EPW + s0 + j] = v;
    }
  }
  __syncthreads();
  for (int i = tid; i < OCT*SP; i += 256) {
    int o = i / SP, sp = i % SP;
    int oc = ocb*OCT + o;
    if (oc < Cout) {
      int syy = sp / SPTW, sxx = sp % SPTW;
      long off = outBase + (long)n*outNStride + (long)oc*outCStride
               + (long)(oy0 + syy)*outYStride + (long)(ox0 + sxx)*outXStride;
      out[off] = smem[o*EPW + sp];
    }
  }
}

// ---------------- NCHW fp32 -> NHWC bf16 planes (swizzled), NP words -------
// Swizzle: within each 32-channel group, channel c stored at slot
// c ^ ((x&3)<<3). Same swizzle for all planes.
template<int NP>
__global__ __launch_bounds__(256) void to_nhwc_bf16(const float* __restrict__ in,
    u16* __restrict__ t, long PS, int C, int HW) {
  __shared__ float sm[32][65];
  const int n = blockIdx.z, c0 = blockIdx.y << 5, w0 = blockIdx.x << 6;
  const long ibase = ((long)n * C + c0) * HW + w0;
  for (int i = threadIdx.x; i < 2048; i += 256) {
    int c = i >> 6, w = i & 63;
    sm[c][w] = in[ibase + (long)c * HW + w];
  }
  __syncthreads();
  for (int i = threadIdx.x; i < 512; i += 256) {
    int w = i >> 3, c4 = (i & 7) << 2;
    short hv[4], mv[4], lv[4];
#pragma unroll
    for (int q = 0; q < 4; ++q) {
      float v = sm[c4 + q][w];
      u16 h = f2bf(v); hv[q] = (short)h;
      float r1 = v - bf2f(h);
      u16 m = f2bf(r1); mv[q] = (short)m;
      if (NP == 3) lv[q] = (short)f2bf(r1 - bf2f(m));
    }
    int scr = c4 ^ ((w & 3) << 3);
    long o = ((long)n * HW + w0 + w) * C + c0 + scr;
    *(s16x4*)(t + o)      = *(s16x4*)hv;
    *(s16x4*)(t + PS + o) = *(s16x4*)mv;
    if (NP == 3) *(s16x4*)(t + 2*PS + o) = *(s16x4*)lv;
  }
}

// ---------------- weight split: [oc][ic][tap] fp32 -> NP x [tap][oc][ic] ---
template<int NP>
__global__ void wsplit(const float* __restrict__ w, u16* __restrict__ dst,
                       long PS, int Cout, int Cin, int TAPS) {
  int total = TAPS * Cout * Cin;
  for (int i = blockIdx.x * 256 + threadIdx.x; i < total; i += gridDim.x * 256) {
    int ic = i % Cin; int rest = i / Cin; int oc = rest % Cout; int tap = rest / Cout;
    float v = w[((long)oc * Cin + ic) * TAPS + tap];
    u16 h = f2bf(v);
    dst[i] = h;
    float r1 = v - bf2f(h);
    u16 m = f2bf(r1);
    dst[PS + i] = m;
    if (NP == 3) dst[2*PS + i] = f2bf(r1 - bf2f(m));
  }
}

// ---------------- MFMA conv: 8x8 spatial x 64 oc, NW-word bf16 -------------
// NW=2: products hH, lH, hL (decoder class).
// NW=3: hH into acc; mH,hM,lH,hL,mM into acc2 (fp32-noise-class, encoder z).
template<int KH, int KW, int ACT, int NW>
__global__ __launch_bounds__(256) void conv_mfma(
    const u16* __restrict__ act, long actPS,
    const u16* __restrict__ wgt, long wgtPS,
    const float* __restrict__ bias, float* __restrict__ out,
    int Cin, int H, int W, int Cout, int WT, int padY, int padX,
    long outBase, long outNS, long outCS, long outYS, long outXS)
{
  constexpr int PH = 8 + KH - 1, PW = 8 + KW - 1;
  constexpr int PPOS = PH * PW;
  constexpr int NU = (PPOS + 15) / 16;           // 1KB units per plane
  constexpr int PLANE = NU * 512;                // u16 per plane
  constexpr int TAPS = KH * KW;
  constexpr int SB = NW * PLANE * 2;             // patch bytes
  constexpr int SFLOATS = (SB > 17408) ? SB / 4 : 4352;
  __shared__ float smem[SFLOATS];
  u16* patch = (u16*)smem;
  float* s_ep = smem;

  const int tid = threadIdx.x;
  const int wv = tid >> 6, ln = tid & 63;
  const int r = ln & 15, kb = ln >> 4;
  const int tile = blockIdx.x, ocb = blockIdx.y, n = blockIdx.z;
  const int oy0 = (tile / WT) * 8, ox0 = (tile % WT) * 8;
  const int y0p = oy0 - padY, x0p = ox0 - padX;
  const bool border = (y0p < 0) | (x0p < 0) | (y0p + PH > H) | (x0p + PW > W);

  const int sp = ln >> 2;                        // staging position sub-index
  const int cs = (ln & 3) * 8;                   // staging channel sub-offset
  const int pos = wv * 16 + r;
  const int sy = pos >> 3, sx = pos & 7;

  f32x4 acc[4] = {};
  f32x4 acc2[4] = {};

  const long actNS = (long)H * W * Cin;
  const long tstep = (long)Cout * Cin;

  for (int c0 = 0; c0 < Cin; c0 += 32) {
    __syncthreads();
    if (border) {
      for (int i = tid; i < NW * PLANE / 8; i += 256)
        ((int4*)patch)[i] = make_int4(0, 0, 0, 0);
      __syncthreads();
    }
    for (int u = wv; u < NW * NU; u += 4) {
      int pl = u / NU, up = u - pl * NU;
      u16* dst = patch + pl * PLANE + up * 512;
      int p = up * 16 + sp;
      int py = p / PW, px = p - py * PW;
      int gy = y0p + py, gx = x0p + px;
      bool valid = (p < PPOS) & ((unsigned)gy < (unsigned)H) & ((unsigned)gx < (unsigned)W);
      if (valid) {
        const u16* src = act + pl * actPS + (long)n * actNS
                       + ((long)gy * W + gx) * Cin + c0 + cs;
        __builtin_amdgcn_global_load_lds((const gu32*)src, (lu32*)dst, 16, 0, 0);
      }
    }
    __syncthreads();

    const long wb = ((long)(ocb * 64 + r)) * Cin + c0 + kb * 8;
#pragma unroll
    for (int t = 0; t < TAPS; ++t) {
      const int ky = t / KW, kx = t % KW;
      const int key = (x0p + sx + kx) & 3;
      const int aoff = ((sy + ky) * PW + (sx + kx)) * 32 + ((kb ^ key) * 8);
      s16x8 a[NW];
      s16x8 B[NW][4];
#pragma unroll
      for (int p = 0; p < NW; ++p) {
        a[p] = *(const s16x8*)(patch + p * PLANE + aoff);
#pragma unroll
        for (int nt = 0; nt < 4; ++nt)
          B[p][nt] = *(const s16x8*)(wgt + p * wgtPS + (long)t * tstep + wb
                                     + nt * 16 * (long)Cin);
      }
#pragma unroll
      for (int nt = 0; nt < 4; ++nt) {
        acc[nt] = __builtin_amdgcn_mfma_f32_16x16x32_bf16(a[0], B[0][nt], acc[nt], 0, 0, 0);
        if constexpr (NW == 2) {
          acc[nt] = __builtin_amdgcn_mfma_f32_16x16x32_bf16(a[1], B[0][nt], acc[nt], 0, 0, 0);
          acc[nt] = __builtin_amdgcn_mfma_f32_16x16x32_bf16(a[0], B[1][nt], acc[nt], 0, 0, 0);
        } else {
          acc2[nt] = __builtin_amdgcn_mfma_f32_16x16x32_bf16(a[1], B[0][nt], acc2[nt], 0, 0, 0);
          acc2[nt] = __builtin_amdgcn_mfma_f32_16x16x32_bf16(a[0], B[1][nt], acc2[nt], 0, 0, 0);
          acc2[nt] = __builtin_amdgcn_mfma_f32_16x16x32_bf16(a[2], B[0][nt], acc2[nt], 0, 0, 0);
          acc2[nt] = __builtin_amdgcn_mfma_f32_16x16x32_bf16(a[0], B[2][nt], acc2[nt], 0, 0, 0);
          acc2[nt] = __builtin_amdgcn_mfma_f32_16x16x32_bf16(a[1], B[1][nt], acc2[nt], 0, 0, 0);
        }
      }
    }
  }

  // epilogue: acc(+acc2)+bias+act -> LDS (oc-major) -> strided store
  __syncthreads();
#pragma unroll
  for (int nt = 0; nt < 4; ++nt) {
    float b = bias[ocb * 64 + nt * 16 + r];
    f32x4 v = acc[nt];
#pragma unroll
    for (int j = 0; j < 4; ++j) {
      float x = v[j];
      if constexpr (NW == 3) x += acc2[nt][j];
      x += b;
      if (ACT == 1) x = fmaxf(x, 0.f);
      v[j] = x;
    }
    *(f32x4*)&s_ep[(nt * 16 + r) * 68 + wv * 16 + kb * 4] = v;
  }
  __syncthreads();
  for (int i = tid; i < 4096; i += 256) {
    int oc = i >> 6, p2 = i & 63;
    int syy = p2 >> 3, sxx = p2 & 7;
    long off = outBase + (long)n * outNS + (long)(ocb * 64 + oc) * outCS
             + (long)(oy0 + syy) * outYS + (long)(ox0 + sxx) * outXS;
    out[off] = s_ep[oc * 68 + p2];
  }
}

// ---------------- convT weight rearrange into 4 parity 2x2 convs ------------
__global__ void rearrange_convT(const float* __restrict__ w, float* __restrict__ wp,
                                int Cin, int Cout) {
  int total = 4*Cout*Cin*4;
  for (int idx = blockIdx.x*256 + threadIdx.x; idx < total; idx += gridDim.x*256) {
    int e = idx & 1, d = (idx >> 1) & 1;
    int r = idx >> 2;
    int ic = r % Cin; r /= Cin;
    int oc = r % Cout; int p = r / Cout;
    int py = p >> 1, px = p & 1;
    int ky = py ? (d ? 0 : 2) : (d ? 1 : 3);
    int kx = px ? (e ? 0 : 2) : (e ? 1 : 3);
    wp[idx] = w[((ic*Cout + oc)*4 + ky)*4 + kx];
  }
}

// ---------------- codebook squared norms ----------------
__global__ __launch_bounds__(256) void cb_norm(const float* __restrict__ cb,
                                               float* __restrict__ outn) {
  int row = blockIdx.x;
  float v = cb[(long)row*256 + threadIdx.x];
  v *= v;
  for (int off = 32; off; off >>= 1) v += __shfl_down(v, off, 64);
  __shared__ float sr[4];
  if ((threadIdx.x & 63) == 0) sr[threadIdx.x >> 6] = v;
  __syncthreads();
  if (threadIdx.x == 0) outn[row] = sr[0] + sr[1] + sr[2] + sr[3];
}

__global__ void zero4(float* __restrict__ p) {
  if (threadIdx.x < 4) p[threadIdx.x] = 0.f;
}

// ---------------- z (NCHW) -> token-major zt + residual copy ----------------
__global__ __launch_bounds__(256) void transpose_zt(const float* __restrict__ z,
                                                    float* __restrict__ zt,
                                                    float* __restrict__ res) {
  __shared__ float t[32][33];
  int b = blockIdx.z, c0 = blockIdx.y*32, hw0 = blockIdx.x*32;
  for (int i = threadIdx.x; i < 1024; i += 256) {
    int cc = i >> 5, ww = i & 31;
    t[cc][ww] = z[((long)(b*256 + c0 + cc) << 12) + hw0 + ww];
  }
  __syncthreads();
  for (int i = threadIdx.x; i < 1024; i += 256) {
    int ww = i >> 5, cc = i & 31;
    float v = t[cc][ww];
    long o = ((long)(b*4096 + hw0 + ww) << 8) + c0 + cc;
    zt[o] = v; res[o] = v;
  }
}

// ---------------- quantized = zt - residual, token-major -> NCHW ------------
__global__ __launch_bounds__(256) void make_quantized(const float* __restrict__ zt,
                                                      const float* __restrict__ res,
                                                      float* __restrict__ q) {
  __shared__ float t[32][33];
  int b = blockIdx.z, c0 = blockIdx.y*32, hw0 = blockIdx.x*32;
  for (int i = threadIdx.x; i < 1024; i += 256) {
    int tt = i >> 5, cc = i & 31;
    long o = ((long)(b*4096 + hw0 + tt) << 8) + c0 + cc;
    t[cc][tt] = zt[o] - res[o];
  }
  __syncthreads();
  for (int i = threadIdx.x; i < 1024; i += 256) {
    int cc = i >> 5, ww = i & 31;
    q[((long)(b*256 + c0 + cc) << 12) + hw0 + ww] = t[cc][ww];
  }
}

// ---------------- one residual-VQ level: fused GEMM + argmin + update -------
__global__ __launch_bounds__(256) void vq_level(
    const float* __restrict__ cb, const float* __restrict__ cbn,
    float* __restrict__ res, float* __restrict__ idx_out,
    float* __restrict__ loss_out)
{
  __shared__ float s_a[4096];
  __shared__ float s_b[4096];
  __shared__ float s_d[64*65];
  __shared__ float s_rv[256];
  __shared__ int   s_ri[256];
  __shared__ float s_min[64];
  __shared__ int   s_mini[64];
  const int tid = threadIdx.x;
  const long t0 = (long)blockIdx.x * 64;
  const int tg = tid & 15, kg = tid >> 4;
  if (tid < 64) { s_min[tid] = 3.4e38f; s_mini[tid] = 0; }

  for (int k0 = 0; k0 < 1024; k0 += 64) {
    float acc[4][4];
#pragma unroll
    for (int i = 0; i < 4; ++i)
#pragma unroll
      for (int j = 0; j < 4; ++j) acc[i][j] = 0.f;

    for (int cs = 0; cs < 256; cs += 64) {
      __syncthreads();
      for (int i = tid; i < 4096; i += 256) {
        int t = i >> 6, c = i & 63;
        int sw = ((t >> 2) & 7) << 2;
        s_a[(t << 6) + (c ^ sw)] = res[((t0 + t) << 8) + cs + c];
        s_b[(t << 6) + (c ^ sw)] = cb[((long)(k0 + t) << 8) + cs + c];
      }
      __syncthreads();
      const int swa = (tg & 7) << 2;
      const int swb = (kg & 7) << 2;
#pragma unroll 4
      for (int c0 = 0; c0 < 64; c0 += 4) {
        float4 ra[4], rb[4];
#pragma unroll
        for (int i = 0; i < 4; ++i)
          ra[i] = *(const float4*)&s_a[((tg*4 + i) << 6) + (c0 ^ swa)];
#pragma unroll
        for (int j = 0; j < 4; ++j)
          rb[j] = *(const float4*)&s_b[((kg*4 + j) << 6) + (c0 ^ swb)];
#pragma unroll
        for (int i = 0; i < 4; ++i)
#pragma unroll
          for (int j = 0; j < 4; ++j) {
            acc[i][j] = fmaf(ra[i].x, rb[j].x, acc[i][j]);
            acc[i][j] = fmaf(ra[i].y, rb[j].y, acc[i][j]);
            acc[i][j] = fmaf(ra[i].z, rb[j].z, acc[i][j]);
            acc[i][j] = fmaf(ra[i].w, rb[j].w, acc[i][j]);
          }
      }
    }
#pragma unroll
    for (int i = 0; i < 4; ++i)
#pragma unroll
      for (int j = 0; j < 4; ++j)
        s_d[(tg*4 + i)*65 + kg*4 + j] = cbn[k0 + kg*4 + j] - 2.f*acc[i][j];
    __syncthreads();
    {
      int tt = tid >> 2, q = tid & 3;
      float mv = 3.4e38f; int mi = 0;
#pragma unroll
      for (int m = 0; m < 16; ++m) {
        int k = q*16 + m;
        float dv = s_d[tt*65 + k];
        if (dv < mv) { mv = dv; mi = k; }
      }
      s_rv[tid] = mv; s_ri[tid] = mi;
    }
    __syncthreads();
    if (tid < 64) {
      float mv = s_rv[tid*4]; int mi = s_ri[tid*4];
#pragma unroll
      for (int q = 1; q < 4; ++q) {
        float v = s_rv[tid*4 + q];
        if (v < mv) { mv = v; mi = s_ri[tid*4 + q]; }
      }
      if (mv < s_min[tid]) { s_min[tid] = mv; s_mini[tid] = k0 + mi; }
    }
    __syncthreads();
  }
  __syncthreads();

  float lsum = 0.f;
  for (int m = 0; m < 64; ++m) {
    int w = s_mini[m];
    long ro = ((t0 + m) << 8) + tid;
    float nv = res[ro] - cb[((long)w << 8) + tid];
    res[ro] = nv;
    lsum += nv*nv;
  }
  for (int off = 32; off; off >>= 1) lsum += __shfl_down(lsum, off, 64);
  __syncthreads();
  if ((tid & 63) == 0) s_rv[tid >> 6] = lsum;
  __syncthreads();
  if (tid == 0) {
    float tot = s_rv[0] + s_rv[1] + s_rv[2] + s_rv[3];
    atomicAdd(loss_out, tot * (1.f/(65536.f*256.f)));
  }
  if (tid < 64) {
    long tglob = t0 + tid;
    int b = (int)(tglob >> 12), hw = (int)(tglob & 4095);
    idx_out[(long)b*16384 + hw] = (float)s_mini[tid];
  }
}

// ---------------------------------------------------------------------------
extern "C" void kernel_launch(void* const* d_in, const int* in_sizes, int n_in,
                              void* d_out, int out_size, void* d_ws, size_t ws_size,
                              hipStream_t stream) {
  const float* x      = (const float*)d_in[0];
  const float* ew1    = (const float*)d_in[1];
  const float* eb1    = (const float*)d_in[2];
  const float* ew2    = (const float*)d_in[3];
  const float* eb2    = (const float*)d_in[4];
  const float* ew3    = (const float*)d_in[5];
  const float* eb3    = (const float*)d_in[6];
  const float* ew4    = (const float*)d_in[7];
  const float* eb4    = (const float*)d_in[8];
  const float* cbooks = (const float*)d_in[9];
  const float* dw1    = (const float*)d_in[10];
  const float* db1    = (const float*)d_in[11];
  const float* dw2    = (const float*)d_in[12];
  const float* db2    = (const float*)d_in[13];
  const float* dw3    = (const float*)d_in[14];
  const float* db3    = (const float*)d_in[15];
  const float* dw4    = (const float*)d_in[16];
  const float* db4    = (const float*)d_in[17];

  float* out = (float*)d_out;
  float* o_recon = out;                  // (16,3,512,512)
  float* o_idx   = out + 12582912;       // (16,4,64,64)
  float* o_loss  = out + 12845056;       // (4,)
  float* o_q     = out + 12845060;       // (16,256,64,64)

  float* ws  = (float*)d_ws;
  // fp32 prep region
  float* wp2 = ws;                        // 131072
  float* wp3 = ws + 131072;               //  65536
  float* wp4 = ws + 196608;               //   3072
  float* cbn = ws + 199680;               //   4096
  // bf16 weight planes (u16), base at float offset 203776
  u16* wu   = (u16*)(ws + 203776);
  u16* e3w  = wu;                         // 3 x 294912
  u16* e4w  = wu + 884736;                // 3 x 589824
  u16* d1w  = wu + 2654208;               // 2 x 294912
  u16* t2w  = wu + 3244032;               // 4 parities x (2 x 32768)
  u16* t3w  = wu + 3506176;               // 4 parities x (2 x 16384)

  const long DA = 2097152;
  float* h1  = ws + DA;
  float* h2  = ws + DA + 16777216;
  float* h3  = ws + DA;                   // h1 dead
  float* z   = ws + DA + 41943040;
  float* zt  = ws + DA;                   // h3 dead
  float* res = ws + DA + 16777216;        // A4 dead
  float* d1  = ws + DA;                   // zt dead
  float* d2  = ws + DA + 16777216;        // res dead
  float* d3  = ws + DA + 16777216;        // d2 consumed into D3 first? no: d3 after D3
  u16* A3 = (u16*)(ws + DA + 25165824);   // 3 x 8388608 u16
  u16* A4 = (u16*)(ws + DA + 16777216);   // 3 x 16777216 u16
  u16* D1 = (u16*)(ws + DA + 33554432);   // 2 x 16777216 u16
  u16* D2 = (u16*)(ws + DA + 8388608);    // 2 x 8388608 u16
  u16* D3 = (u16*)(ws + DA);              // 2 x 16777216 u16

  // ---------------- prep ----------------
  rearrange_convT<<<256, 256, 0, stream>>>(dw2, wp2, 128, 64);
  rearrange_convT<<<256, 256, 0, stream>>>(dw3, wp3, 64, 64);
  rearrange_convT<<<16, 256, 0, stream>>>(dw4, wp4, 64, 3);
  cb_norm<<<4096, 256, 0, stream>>>(cbooks, cbn);
  zero4<<<1, 64, 0, stream>>>(o_loss);
  wsplit<3><<<256, 256, 0, stream>>>(ew3, e3w, 294912L, 256, 128, 9);
  wsplit<3><<<256, 256, 0, stream>>>(ew4, e4w, 589824L, 256, 256, 9);
  wsplit<2><<<256, 256, 0, stream>>>(dw1, d1w, 294912L, 128, 256, 9);
  for (int p = 0; p < 4; ++p) {
    wsplit<2><<<64, 256, 0, stream>>>(wp2 + p*32768, t2w + p*65536, 32768L, 64, 128, 4);
    wsplit<2><<<64, 256, 0, stream>>>(wp3 + p*16384, t3w + p*32768, 16384L, 64, 64, 4);
  }

  // ---------------- encoder ----------------
  conv_tiled<64,8,8,4,4,2,1><<<dim3(256,1,16), 256, 0, stream>>>(
      x, ew1, eb1, h1, 16, 3, 256, 256, 64, 16, 1, 1,
      0L, 1048576L, 16384L, 128L, 1L);
  conv_tiled<64,8,8,4,4,2,1><<<dim3(64,2,16), 256, 0, stream>>>(
      h1, ew2, eb2, h2, 16, 64, 128, 128, 128, 8, 1, 1,
      0L, 524288L, 4096L, 64L, 1L);

  to_nhwc_bf16<3><<<dim3(64,4,16), 256, 0, stream>>>(h2, A3, 8388608L, 128, 4096);
  conv_mfma<3,3,1,3><<<dim3(64,4,16), 256, 0, stream>>>(
      A3, 8388608L, e3w, 294912L, eb3, h3,
      128, 64, 64, 256, 8, 1, 1, 0L, 1048576L, 4096L, 64L, 1L);

  to_nhwc_bf16<3><<<dim3(64,8,16), 256, 0, stream>>>(h3, A4, 16777216L, 256, 4096);
  conv_mfma<3,3,0,3><<<dim3(64,4,16), 256, 0, stream>>>(
      A4, 16777216L, e4w, 589824L, eb4, z,
      256, 64, 64, 256, 8, 1, 1, 0L, 1048576L, 4096L, 64L, 1L);

  // ---------------- VQ ----------------
  transpose_zt<<<dim3(128,8,16), 256, 0, stream>>>(z, zt, res);
  for (int l = 0; l < 4; ++l)
    vq_level<<<1024, 256, 0, stream>>>(cbooks + (long)l*262144, cbn + l*1024,
                                       res, o_idx + l*4096, o_loss + l);
  make_quantized<<<dim3(128,8,16), 256, 0, stream>>>(zt, res, o_q);

  // ---------------- decoder ----------------
  to_nhwc_bf16<2><<<dim3(64,8,16), 256, 0, stream>>>(o_q, D1, 16777216L, 256, 4096);
  conv_mfma<3,3,1,2><<<dim3(64,2,16), 256, 0, stream>>>(
      D1, 16777216L, d1w, 294912L, db1, d1,
      256, 64, 64, 128, 8, 1, 1, 0L, 524288L, 4096L, 64L, 1L);

  to_nhwc_bf16<2><<<dim3(64,4,16), 256, 0, stream>>>(d1, D2, 8388608L, 128, 4096);
  for (int p = 0; p < 4; ++p) {
    int py = p >> 1, px = p & 1;
    conv_mfma<2,2,1,2><<<dim3(64,1,16), 256, 0, stream>>>(
        D2, 8388608L, t2w + p*65536, 32768L, db2, d2,
        128, 64, 64, 64, 8, 1-py, 1-px,
        (long)(py*128 + px), 1048576L, 16384L, 256L, 2L);
  }

  to_nhwc_bf16<2><<<dim3(256,2,16), 256, 0, stream>>>(d2, D3, 16777216L, 64, 16384);
  for (int p = 0; p < 4; ++p) {
    int py = p >> 1, px = p & 1;
    conv_mfma<2,2,1,2><<<dim3(256,1,16), 256, 0, stream>>>(
        D3, 16777216L, t3w + p*32768, 16384L, db3, d3,
        64, 128, 128, 64, 16, 1-py, 1-px,
        (long)(py*256 + px), 4194304L, 65536L, 512L, 2L);
  }

  for (int p = 0; p < 4; ++p) {
    int py = p >> 1, px = p & 1;
    conv_tiled<4,16,16,2,2,1,2><<<dim3(256,1,16), 256, 0, stream>>>(
        d3, wp4 + p*768, db4, o_recon, 16, 64, 256, 256, 3, 16, 1-py, 1-px,
        (long)(py*512 + px), 786432L, 262144L, 1024L, 2L);
  }
  (void)in_sizes; (void)n_in; (void)out_size; (void)ws_size;
}

// Round 4
// 6301.078 us; speedup vs baseline: 1.4088x; 1.4088x over previous
//
#include <hip/hip_runtime.h>
#include <cmath>

// ---------------------------------------------------------------------------
// RQ-VAE forward, round 4.
// conv_mfma restructured for latency: wave owns an N-quadrant (16 oc) and all
// 64 positions (4 M-tiles); B-fragments prefetched 1 tap ahead (4x fewer
// global loads/wave, each reused 4x); patch double-buffered with async
// global_load_lds staged under compute. MFMA sequence/order identical to
// round 3 -> bit-identical z -> index-exact.
// ---------------------------------------------------------------------------

typedef unsigned short u16;
typedef unsigned int   u32;
typedef __attribute__((ext_vector_type(8))) short s16x8;
typedef __attribute__((ext_vector_type(4))) short s16x4;
typedef __attribute__((ext_vector_type(4))) float f32x4;
typedef __attribute__((address_space(1))) const u32 gu32;
typedef __attribute__((address_space(3))) u32 lu32;

__device__ __forceinline__ u16 f2bf(float v) {   // RNE fp32->bf16 bits
  u32 b = __builtin_bit_cast(u32, v);
  b += 0x7FFFu + ((b >> 16) & 1u);
  return (u16)(b >> 16);
}
__device__ __forceinline__ float bf2f(u16 h) {
  u32 b = ((u32)h) << 16;
  return __builtin_bit_cast(float, b);
}

// ---------------- row vector load from LDS (aligned) ----------------
template<int RW>
__device__ __forceinline__ void load_row(const float* __restrict__ p, float* r) {
  if constexpr (RW == 5) {
    float4 a = *(const float4*)p;
    r[0]=a.x; r[1]=a.y; r[2]=a.z; r[3]=a.w; r[4]=p[4];
  } else if constexpr (RW == 6) {
    float4 a = *(const float4*)p; float2 b = *(const float2*)(p+4);
    r[0]=a.x; r[1]=a.y; r[2]=a.z; r[3]=a.w; r[4]=b.x; r[5]=b.y;
  } else if constexpr (RW == 10) {
    float4 a = *(const float4*)p; float4 b = *(const float4*)(p+4);
    float2 c = *(const float2*)(p+8);
    r[0]=a.x; r[1]=a.y; r[2]=a.z; r[3]=a.w;
    r[4]=b.x; r[5]=b.y; r[6]=b.z; r[7]=b.w; r[8]=c.x; r[9]=c.y;
  }
}

// ---------------- generic tiled direct conv (fp32 light layers) ----------
template<int OCT, int SPTH, int SPTW, int KH, int KW, int S, int ACT>
__global__ __launch_bounds__(256) void conv_tiled(
    const float* __restrict__ in, const float* __restrict__ wgt,
    const float* __restrict__ bias, float* __restrict__ out,
    int N, int Cin, int Hin, int Win, int Cout, int WT,
    int padY, int padX,
    long outBase, long outNStride, long outCStride, long outYStride, long outXStride)
{
  constexpr int CK   = 8;
  constexpr int IH   = (SPTH-1)*S + KH;
  constexpr int IWr  = (SPTW-1)*S + KW;
  constexpr int IW   = (IWr + 3) & ~3;
  constexpr int TAPS = KH*KW;
  constexpr int WST  = (OCT==64) ? 68 : 5;
  constexpr int LOC  = (OCT==64) ? 16 : 4;
  constexpr int OPT  = OCT/LOC;
  constexpr int RW   = 3*S + KW;
  constexpr int EPW  = (OCT==64) ? 65 : 257;
  constexpr int SP   = SPTH*SPTW;
  constexpr int STG  = CK*IH*IW + CK*TAPS*WST;
  constexpr int SMEMN = (STG > OCT*EPW) ? STG : OCT*EPW;
  __shared__ float smem[SMEMN];
  float* s_in = smem;
  float* s_w  = smem + CK*IH*IW;

  const int tid  = threadIdx.x;
  const int tile = blockIdx.x, ocb = blockIdx.y, n = blockIdx.z;
  const int oy0 = (tile / WT) * SPTH, ox0 = (tile % WT) * SPTW;
  const int ol  = tid % LOC;
  const int g   = tid / LOC;
  const int s0  = g * 4;
  const int sy  = s0 / SPTW, sx0 = s0 % SPTW;
  const int iy0 = oy0*S - padY, ix0 = ox0*S - padX;

  float acc[OPT][4];
#pragma unroll
  for (int o = 0; o < OPT; ++o)
#pragma unroll
    for (int j = 0; j < 4; ++j) acc[o][j] = 0.f;

  for (int c0 = 0; c0 < Cin; c0 += CK) {
    __syncthreads();
    for (int i = tid; i < CK*IH*IW; i += 256) {
      int c = i / (IH*IW), r2 = i % (IH*IW);
      int iy = r2 / IW, ix = r2 % IW;
      int gy = iy0 + iy, gx = ix0 + ix;
      float v = 0.f;
      if (c0 + c < Cin && (unsigned)gy < (unsigned)Hin && (unsigned)gx < (unsigned)Win)
        v = in[(((long)n*Cin + c0 + c)*Hin + gy)*Win + gx];
      s_in[i] = v;
    }
    for (int i = tid; i < OCT*CK*TAPS; i += 256) {
      int o = i / (CK*TAPS), ct = i % (CK*TAPS);
      int oc = ocb*OCT + o, ci = c0 + ct / TAPS;
      float v = 0.f;
      if (oc < Cout && ci < Cin)
        v = wgt[((long)oc*Cin + ci)*TAPS + (ct % TAPS)];
      s_w[ct*WST + o] = v;
    }
    __syncthreads();

    for (int c = 0; c < CK; ++c) {
#pragma unroll
      for (int ky = 0; ky < KH; ++ky) {
        float r[RW];
        load_row<RW>(&s_in[c*(IH*IW) + (sy*S + ky)*IW + sx0*S], r);
#pragma unroll
        for (int kx = 0; kx < KW; ++kx) {
          if constexpr (OCT == 64) {
            float4 w4 = *(const float4*)&s_w[(c*TAPS + ky*KW + kx)*WST + ol*4];
            float wv[4] = {w4.x, w4.y, w4.z, w4.w};
#pragma unroll
            for (int o = 0; o < 4; ++o)
#pragma unroll
              for (int j = 0; j < 4; ++j)
                acc[o][j] = fmaf(wv[o], r[j*S + kx], acc[o][j]);
          } else {
            float w = s_w[(c*TAPS + ky*KW + kx)*WST + ol];
#pragma unroll
            for (int j = 0; j < 4; ++j)
              acc[0][j] = fmaf(w, r[j*S + kx], acc[0][j]);
          }
        }
      }
    }
  }

  __syncthreads();
#pragma unroll
  for (int o = 0; o < OPT; ++o) {
    int oc = ocb*OCT + ol*OPT + o;
    float b = (oc < Cout) ? bias[oc] : 0.f;
#pragma unroll
    for (int j = 0; j < 4; ++j) {
      float v = acc[o][j] + b;
      if constexpr (ACT == 1) v = fmaxf(v, 0.f);
      else if constexpr (ACT == 2) v = tanhf(v);
      smem[(ol*OPT + o)*EPW + s0 + j] = v;
    }
  }
  __syncthreads();
  for (int i = tid; i < OCT*SP; i += 256) {
    int o = i / SP, sp = i % SP;
    int oc = ocb*OCT + o;
    if (oc < Cout) {
      int syy = sp / SPTW, sxx = sp % SPTW;
      long off = outBase + (long)n*outNStride + (long)oc*outCStride
               + (long)(oy0 + syy)*outYStride + (long)(ox0 + sxx)*outXStride;
      out[off] = smem[o*EPW + sp];
    }
  }
}

// ---------------- NCHW fp32 -> NHWC bf16 planes (swizzled), NP words -------
template<int NP>
__global__ __launch_bounds__(256) void to_nhwc_bf16(const float* __restrict__ in,
    u16* __restrict__ t, long PS, int C, int HW) {
  __shared__ float sm[32][65];
  const int n = blockIdx.z, c0 = blockIdx.y << 5, w0 = blockIdx.x << 6;
  const long ibase = ((long)n * C + c0) * HW + w0;
  for (int i = threadIdx.x; i < 2048; i += 256) {
    int c = i >> 6, w = i & 63;
    sm[c][w] = in[ibase + (long)c * HW + w];
  }
  __syncthreads();
  for (int i = threadIdx.x; i < 512; i += 256) {
    int w = i >> 3, c4 = (i & 7) << 2;
    short hv[4], mv[4], lv[4];
#pragma unroll
    for (int q = 0; q < 4; ++q) {
      float v = sm[c4 + q][w];
      u16 h = f2bf(v); hv[q] = (short)h;
      float r1 = v - bf2f(h);
      u16 m = f2bf(r1); mv[q] = (short)m;
      if (NP == 3) lv[q] = (short)f2bf(r1 - bf2f(m));
    }
    int scr = c4 ^ ((w & 3) << 3);
    long o = ((long)n * HW + w0 + w) * C + c0 + scr;
    *(s16x4*)(t + o)      = *(s16x4*)hv;
    *(s16x4*)(t + PS + o) = *(s16x4*)mv;
    if (NP == 3) *(s16x4*)(t + 2*PS + o) = *(s16x4*)lv;
  }
}

// ---------------- weight split: [oc][ic][tap] fp32 -> NP x [tap][oc][ic] ---
template<int NP>
__global__ void wsplit(const float* __restrict__ w, u16* __restrict__ dst,
                       long PS, int Cout, int Cin, int TAPS) {
  int total = TAPS * Cout * Cin;
  for (int i = blockIdx.x * 256 + threadIdx.x; i < total; i += gridDim.x * 256) {
    int ic = i % Cin; int rest = i / Cin; int oc = rest % Cout; int tap = rest / Cout;
    float v = w[((long)oc * Cin + ic) * TAPS + tap];
    u16 h = f2bf(v);
    dst[i] = h;
    float r1 = v - bf2f(h);
    u16 m = f2bf(r1);
    dst[PS + i] = m;
    if (NP == 3) dst[2*PS + i] = f2bf(r1 - bf2f(m));
  }
}

// ---------------- MFMA conv: 8x8 spatial x 64 oc, NW-word bf16 -------------
// Wave wv owns oc quadrant [ocb*64+wv*16, +16), computes all 64 positions
// (4 M-tiles). B fragments: 1-tap register prefetch. Patch: double-buffered,
// staged via async global_load_lds overlapped with compute.
// NW=2: products hH, lH, hL. NW=3: hH->acc; mH,hM,lH,hL,mM->acc2.
template<int KH, int KW, int ACT, int NW>
__global__ __launch_bounds__(256, 3) void conv_mfma(
    const u16* __restrict__ act, long actPS,
    const u16* __restrict__ wgt, long wgtPS,
    const float* __restrict__ bias, float* __restrict__ out,
    int Cin, int H, int W, int Cout, int WT, int padY, int padX,
    long outBase, long outNS, long outCS, long outYS, long outXS)
{
  constexpr int PH = 8 + KH - 1, PW = 8 + KW - 1;
  constexpr int PPOS = PH * PW;
  constexpr int NU = (PPOS + 15) / 16;          // 1KB units per plane
  constexpr int PLANE = NU * 512;               // u16 per plane
  constexpr int BUFU = NW * PLANE;              // u16 per buffer
  constexpr int TAPS = KH * KW;
  constexpr int PATCHB = 2 * BUFU * 2;          // bytes, two buffers
  constexpr int SFLOATS = ((PATCHB > 17408) ? PATCHB : 17408) / 4;
  __shared__ float smem[SFLOATS];
  u16* patch = (u16*)smem;
  float* s_ep = smem;

  const int tid = threadIdx.x;
  const int wv = tid >> 6, ln = tid & 63;
  const int r = ln & 15, kb = ln >> 4;
  const int tile = blockIdx.x, ocb = blockIdx.y, n = blockIdx.z;
  const int oy0 = (tile / WT) * 8, ox0 = (tile % WT) * 8;
  const int y0p = oy0 - padY, x0p = ox0 - padX;
  const bool border = (y0p < 0) | (x0p < 0) | (y0p + PH > H) | (x0p + PW > W);

  const int sp = ln >> 2;                       // staging position sub-index
  const int cs = (ln & 3) * 8;                  // staging channel sub-offset

  // per-M-tile A geometry (lane's row r within each 16-position group)
  int aoff0[4], xb[4];
#pragma unroll
  for (int m = 0; m < 4; ++m) {
    int pos = m * 16 + r;
    int sy = pos >> 3, sx = pos & 7;
    aoff0[m] = (sy * PW + sx) * 32;
    xb[m] = x0p + sx;
  }

  f32x4 acc[4] = {};
  f32x4 acc2[4] = {};

  const long actNS = (long)H * W * Cin;
  const long tstep = (long)Cout * Cin;
  const u16* wrow = wgt + (long)(ocb * 64 + wv * 16 + r) * Cin + kb * 8;
  const u16* gact = act + (long)n * actNS;

  if (border) {                                 // zero both buffers once
    for (int i = tid; i < 2 * BUFU / 8; i += 256)
      ((int4*)patch)[i] = make_int4(0, 0, 0, 0);
  }
  __syncthreads();

  auto stage = [&](int b, int c0) {
    u16* bb = patch + b * BUFU;
    for (int u = wv; u < NW * NU; u += 4) {
      int pl = u / NU, up = u - pl * NU;
      u16* dst = bb + pl * PLANE + up * 512;    // wave-uniform base
      int p = up * 16 + sp;
      int py = p / PW, px = p - py * PW;
      int gy = y0p + py, gx = x0p + px;
      bool valid = (p < PPOS) & ((unsigned)gy < (unsigned)H) & ((unsigned)gx < (unsigned)W);
      if (valid) {
        const u16* src = gact + pl * actPS + ((long)gy * W + gx) * Cin + c0 + cs;
        __builtin_amdgcn_global_load_lds((const gu32*)src, (lu32*)dst, 16, 0, 0);
      }
    }
  };

  stage(0, 0);
  int buf = 0;
  for (int c0 = 0; c0 < Cin; c0 += 32) {
    __syncthreads();                            // drains vmcnt: patch[buf] ready
    s16x8 Bb[2][NW];
    {                                           // tap 0 B fragments
      const u16* base = wrow + c0;
#pragma unroll
      for (int p = 0; p < NW; ++p) Bb[0][p] = *(const s16x8*)(base + p * wgtPS);
    }
    if (c0 + 32 < Cin) stage(buf ^ 1, c0 + 32); // async next-step staging
    const u16* pb = patch + buf * BUFU;
#pragma unroll
    for (int t = 0; t < TAPS; ++t) {
      if (t + 1 < TAPS) {                       // prefetch next tap's B
        const u16* base = wrow + (long)(t + 1) * tstep + c0;
#pragma unroll
        for (int p = 0; p < NW; ++p)
          Bb[(t + 1) & 1][p] = *(const s16x8*)(base + p * wgtPS);
      }
      const int ky = t / KW, kx = t % KW;
#pragma unroll
      for (int m = 0; m < 4; ++m) {
        const int key = (xb[m] + kx) & 3;
        const int aoff = aoff0[m] + (ky * PW + kx) * 32 + ((kb ^ key) * 8);
        s16x8 a[NW];
#pragma unroll
        for (int p = 0; p < NW; ++p)
          a[p] = *(const s16x8*)(pb + p * PLANE + aoff);
        acc[m] = __builtin_amdgcn_mfma_f32_16x16x32_bf16(a[0], Bb[t & 1][0], acc[m], 0, 0, 0);
        if constexpr (NW == 2) {
          acc[m] = __builtin_amdgcn_mfma_f32_16x16x32_bf16(a[1], Bb[t & 1][0], acc[m], 0, 0, 0);
          acc[m] = __builtin_amdgcn_mfma_f32_16x16x32_bf16(a[0], Bb[t & 1][1], acc[m], 0, 0, 0);
        } else {
          acc2[m] = __builtin_amdgcn_mfma_f32_16x16x32_bf16(a[1], Bb[t & 1][0], acc2[m], 0, 0, 0);
          acc2[m] = __builtin_amdgcn_mfma_f32_16x16x32_bf16(a[0], Bb[t & 1][1], acc2[m], 0, 0, 0);
          acc2[m] = __builtin_amdgcn_mfma_f32_16x16x32_bf16(a[2], Bb[t & 1][0], acc2[m], 0, 0, 0);
          acc2[m] = __builtin_amdgcn_mfma_f32_16x16x32_bf16(a[0], Bb[t & 1][2], acc2[m], 0, 0, 0);
          acc2[m] = __builtin_amdgcn_mfma_f32_16x16x32_bf16(a[1], Bb[t & 1][1], acc2[m], 0, 0, 0);
        }
      }
    }
    buf ^= 1;
  }

  // epilogue: acc(+acc2)+bias+act -> LDS (oc-major) -> strided store
  __syncthreads();
  const float bsv = bias[ocb * 64 + wv * 16 + r];
#pragma unroll
  for (int m = 0; m < 4; ++m) {
    f32x4 v = acc[m];
#pragma unroll
    for (int j = 0; j < 4; ++j) {
      float x = v[j];
      if constexpr (NW == 3) x += acc2[m][j];
      x += bsv;
      if (ACT == 1) x = fmaxf(x, 0.f);
      v[j] = x;
    }
    *(f32x4*)&s_ep[(wv * 16 + r) * 68 + m * 16 + kb * 4] = v;
  }
  __syncthreads();
  for (int i = tid; i < 4096; i += 256) {
    int oc = i >> 6, p2 = i & 63;
    int syy = p2 >> 3, sxx = p2 & 7;
    long off = outBase + (long)n * outNS + (long)(ocb * 64 + oc) * outCS
             + (long)(oy0 + syy) * outYS + (long)(ox0 + sxx) * outXS;
    out[off] = s_ep[oc * 68 + p2];
  }
}

// ---------------- convT weight rearrange into 4 parity 2x2 convs ------------
__global__ void rearrange_convT(const float* __restrict__ w, float* __restrict__ wp,
                                int Cin, int Cout) {
  int total = 4*Cout*Cin*4;
  for (int idx = blockIdx.x*256 + threadIdx.x; idx < total; idx += gridDim.x*256) {
    int e = idx & 1, d = (idx >> 1) & 1;
    int r = idx >> 2;
    int ic = r % Cin; r /= Cin;
    int oc = r % Cout; int p = r / Cout;
    int py = p >> 1, px = p & 1;
    int ky = py ? (d ? 0 : 2) : (d ? 1 : 3);
    int kx = px ? (e ? 0 : 2) : (e ? 1 : 3);
    wp[idx] = w[((ic*Cout + oc)*4 + ky)*4 + kx];
  }
}

// ---------------- codebook squared norms ----------------
__global__ __launch_bounds__(256) void cb_norm(const float* __restrict__ cb,
                                               float* __restrict__ outn) {
  int row = blockIdx.x;
  float v = cb[(long)row*256 + threadIdx.x];
  v *= v;
  for (int off = 32; off; off >>= 1) v += __shfl_down(v, off, 64);
  __shared__ float sr[4];
  if ((threadIdx.x & 63) == 0) sr[threadIdx.x >> 6] = v;
  __syncthreads();
  if (threadIdx.x == 0) outn[row] = sr[0] + sr[1] + sr[2] + sr[3];
}

__global__ void zero4(float* __restrict__ p) {
  if (threadIdx.x < 4) p[threadIdx.x] = 0.f;
}

// ---------------- z (NCHW) -> token-major zt + residual copy ----------------
__global__ __launch_bounds__(256) void transpose_zt(const float* __restrict__ z,
                                                    float* __restrict__ zt,
                                                    float* __restrict__ res) {
  __shared__ float t[32][33];
  int b = blockIdx.z, c0 = blockIdx.y*32, hw0 = blockIdx.x*32;
  for (int i = threadIdx.x; i < 1024; i += 256) {
    int cc = i >> 5, ww = i & 31;
    t[cc][ww] = z[((long)(b*256 + c0 + cc) << 12) + hw0 + ww];
  }
  __syncthreads();
  for (int i = threadIdx.x; i < 1024; i += 256) {
    int ww = i >> 5, cc = i & 31;
    float v = t[cc][ww];
    long o = ((long)(b*4096 + hw0 + ww) << 8) + c0 + cc;
    zt[o] = v; res[o] = v;
  }
}

// ---------------- quantized = zt - residual, token-major -> NCHW ------------
__global__ __launch_bounds__(256) void make_quantized(const float* __restrict__ zt,
                                                      const float* __restrict__ res,
                                                      float* __restrict__ q) {
  __shared__ float t[32][33];
  int b = blockIdx.z, c0 = blockIdx.y*32, hw0 = blockIdx.x*32;
  for (int i = threadIdx.x; i < 1024; i += 256) {
    int tt = i >> 5, cc = i & 31;
    long o = ((long)(b*4096 + hw0 + tt) << 8) + c0 + cc;
    t[cc][tt] = zt[o] - res[o];
  }
  __syncthreads();
  for (int i = threadIdx.x; i < 1024; i += 256) {
    int cc = i >> 5, ww = i & 31;
    q[((long)(b*256 + c0 + cc) << 12) + hw0 + ww] = t[cc][ww];
  }
}

// ---------------- one residual-VQ level: fused GEMM + argmin + update -------
__global__ __launch_bounds__(256) void vq_level(
    const float* __restrict__ cb, const float* __restrict__ cbn,
    float* __restrict__ res, float* __restrict__ idx_out,
    float* __restrict__ loss_out)
{
  __shared__ float s_a[4096];
  __shared__ float s_b[4096];
  __shared__ float s_d[64*65];
  __shared__ float s_rv[256];
  __shared__ int   s_ri[256];
  __shared__ float s_min[64];
  __shared__ int   s_mini[64];
  const int tid = threadIdx.x;
  const long t0 = (long)blockIdx.x * 64;
  const int tg = tid & 15, kg = tid >> 4;
  if (tid < 64) { s_min[tid] = 3.4e38f; s_mini[tid] = 0; }

  for (int k0 = 0; k0 < 1024; k0 += 64) {
    float acc[4][4];
#pragma unroll
    for (int i = 0; i < 4; ++i)
#pragma unroll
      for (int j = 0; j < 4; ++j) acc[i][j] = 0.f;

    for (int cs = 0; cs < 256; cs += 64) {
      __syncthreads();
      for (int i = tid; i < 4096; i += 256) {
        int t = i >> 6, c = i & 63;
        int sw = ((t >> 2) & 7) << 2;
        s_a[(t << 6) + (c ^ sw)] = res[((t0 + t) << 8) + cs + c];
        s_b[(t << 6) + (c ^ sw)] = cb[((long)(k0 + t) << 8) + cs + c];
      }
      __syncthreads();
      const int swa = (tg & 7) << 2;
      const int swb = (kg & 7) << 2;
#pragma unroll 4
      for (int c0 = 0; c0 < 64; c0 += 4) {
        float4 ra[4], rb[4];
#pragma unroll
        for (int i = 0; i < 4; ++i)
          ra[i] = *(const float4*)&s_a[((tg*4 + i) << 6) + (c0 ^ swa)];
#pragma unroll
        for (int j = 0; j < 4; ++j)
          rb[j] = *(const float4*)&s_b[((kg*4 + j) << 6) + (c0 ^ swb)];
#pragma unroll
        for (int i = 0; i < 4; ++i)
#pragma unroll
          for (int j = 0; j < 4; ++j) {
            acc[i][j] = fmaf(ra[i].x, rb[j].x, acc[i][j]);
            acc[i][j] = fmaf(ra[i].y, rb[j].y, acc[i][j]);
            acc[i][j] = fmaf(ra[i].z, rb[j].z, acc[i][j]);
            acc[i][j] = fmaf(ra[i].w, rb[j].w, acc[i][j]);
          }
      }
    }
#pragma unroll
    for (int i = 0; i < 4; ++i)
#pragma unroll
      for (int j = 0; j < 4; ++j)
        s_d[(tg*4 + i)*65 + kg*4 + j] = cbn[k0 + kg*4 + j] - 2.f*acc[i][j];
    __syncthreads();
    {
      int tt = tid >> 2, q = tid & 3;
      float mv = 3.4e38f; int mi = 0;
#pragma unroll
      for (int m = 0; m < 16; ++m) {
        int k = q*16 + m;
        float dv = s_d[tt*65 + k];
        if (dv < mv) { mv = dv; mi = k; }
      }
      s_rv[tid] = mv; s_ri[tid] = mi;
    }
    __syncthreads();
    if (tid < 64) {
      float mv = s_rv[tid*4]; int mi = s_ri[tid*4];
#pragma unroll
      for (int q = 1; q < 4; ++q) {
        float v = s_rv[tid*4 + q];
        if (v < mv) { mv = v; mi = s_ri[tid*4 + q]; }
      }
      if (mv < s_min[tid]) { s_min[tid] = mv; s_mini[tid] = k0 + mi; }
    }
    __syncthreads();
  }
  __syncthreads();

  float lsum = 0.f;
  for (int m = 0; m < 64; ++m) {
    int w = s_mini[m];
    long ro = ((t0 + m) << 8) + tid;
    float nv = res[ro] - cb[((long)w << 8) + tid];
    res[ro] = nv;
    lsum += nv*nv;
  }
  for (int off = 32; off; off >>= 1) lsum += __shfl_down(lsum, off, 64);
  __syncthreads();
  if ((tid & 63) == 0) s_rv[tid >> 6] = lsum;
  __syncthreads();
  if (tid == 0) {
    float tot = s_rv[0] + s_rv[1] + s_rv[2] + s_rv[3];
    atomicAdd(loss_out, tot * (1.f/(65536.f*256.f)));
  }
  if (tid < 64) {
    long tglob = t0 + tid;
    int b = (int)(tglob >> 12), hw = (int)(tglob & 4095);
    idx_out[(long)b*16384 + hw] = (float)s_mini[tid];
  }
}

// ---------------------------------------------------------------------------
extern "C" void kernel_launch(void* const* d_in, const int* in_sizes, int n_in,
                              void* d_out, int out_size, void* d_ws, size_t ws_size,
                              hipStream_t stream) {
  const float* x      = (const float*)d_in[0];
  const float* ew1    = (const float*)d_in[1];
  const float* eb1    = (const float*)d_in[2];
  const float* ew2    = (const float*)d_in[3];
  const float* eb2    = (const float*)d_in[4];
  const float* ew3    = (const float*)d_in[5];
  const float* eb3    = (const float*)d_in[6];
  const float* ew4    = (const float*)d_in[7];
  const float* eb4    = (const float*)d_in[8];
  const float* cbooks = (const float*)d_in[9];
  const float* dw1    = (const float*)d_in[10];
  const float* db1    = (const float*)d_in[11];
  const float* dw2    = (const float*)d_in[12];
  const float* db2    = (const float*)d_in[13];
  const float* dw3    = (const float*)d_in[14];
  const float* db3    = (const float*)d_in[15];
  const float* dw4    = (const float*)d_in[16];
  const float* db4    = (const float*)d_in[17];

  float* out = (float*)d_out;
  float* o_recon = out;                  // (16,3,512,512)
  float* o_idx   = out + 12582912;       // (16,4,64,64)
  float* o_loss  = out + 12845056;       // (4,)
  float* o_q     = out + 12845060;       // (16,256,64,64)

  float* ws  = (float*)d_ws;
  // fp32 prep region
  float* wp2 = ws;                        // 131072
  float* wp3 = ws + 131072;               //  65536
  float* wp4 = ws + 196608;               //   3072
  float* cbn = ws + 199680;               //   4096
  // bf16 weight planes (u16), base at float offset 203776
  u16* wu   = (u16*)(ws + 203776);
  u16* e3w  = wu;                         // 3 x 294912
  u16* e4w  = wu + 884736;                // 3 x 589824
  u16* d1w  = wu + 2654208;               // 2 x 294912
  u16* t2w  = wu + 3244032;               // 4 parities x (2 x 32768)
  u16* t3w  = wu + 3506176;               // 4 parities x (2 x 16384)

  const long DA = 2097152;
  float* h1  = ws + DA;
  float* h2  = ws + DA + 16777216;
  float* h3  = ws + DA;                   // h1 dead
  float* z   = ws + DA + 41943040;
  float* zt  = ws + DA;                   // h3 dead
  float* res = ws + DA + 16777216;        // A4 dead
  float* d1  = ws + DA;                   // zt dead
  float* d2  = ws + DA + 16777216;        // res dead
  float* d3  = ws + DA + 16777216;        // after D3 consumed
  u16* A3 = (u16*)(ws + DA + 25165824);   // 3 x 8388608 u16
  u16* A4 = (u16*)(ws + DA + 16777216);   // 3 x 16777216 u16
  u16* D1 = (u16*)(ws + DA + 33554432);   // 2 x 16777216 u16
  u16* D2 = (u16*)(ws + DA + 8388608);    // 2 x 8388608 u16
  u16* D3 = (u16*)(ws + DA);              // 2 x 16777216 u16

  // ---------------- prep ----------------
  rearrange_convT<<<256, 256, 0, stream>>>(dw2, wp2, 128, 64);
  rearrange_convT<<<256, 256, 0, stream>>>(dw3, wp3, 64, 64);
  rearrange_convT<<<16, 256, 0, stream>>>(dw4, wp4, 64, 3);
  cb_norm<<<4096, 256, 0, stream>>>(cbooks, cbn);
  zero4<<<1, 64, 0, stream>>>(o_loss);
  wsplit<3><<<256, 256, 0, stream>>>(ew3, e3w, 294912L, 256, 128, 9);
  wsplit<3><<<256, 256, 0, stream>>>(ew4, e4w, 589824L, 256, 256, 9);
  wsplit<2><<<256, 256, 0, stream>>>(dw1, d1w, 294912L, 128, 256, 9);
  for (int p = 0; p < 4; ++p) {
    wsplit<2><<<64, 256, 0, stream>>>(wp2 + p*32768, t2w + p*65536, 32768L, 64, 128, 4);
    wsplit<2><<<64, 256, 0, stream>>>(wp3 + p*16384, t3w + p*32768, 16384L, 64, 64, 4);
  }

  // ---------------- encoder ----------------
  conv_tiled<64,8,8,4,4,2,1><<<dim3(256,1,16), 256, 0, stream>>>(
      x, ew1, eb1, h1, 16, 3, 256, 256, 64, 16, 1, 1,
      0L, 1048576L, 16384L, 128L, 1L);
  conv_tiled<64,8,8,4,4,2,1><<<dim3(64,2,16), 256, 0, stream>>>(
      h1, ew2, eb2, h2, 16, 64, 128, 128, 128, 8, 1, 1,
      0L, 524288L, 4096L, 64L, 1L);

  to_nhwc_bf16<3><<<dim3(64,4,16), 256, 0, stream>>>(h2, A3, 8388608L, 128, 4096);
  conv_mfma<3,3,1,3><<<dim3(64,4,16), 256, 0, stream>>>(
      A3, 8388608L, e3w, 294912L, eb3, h3,
      128, 64, 64, 256, 8, 1, 1, 0L, 1048576L, 4096L, 64L, 1L);

  to_nhwc_bf16<3><<<dim3(64,8,16), 256, 0, stream>>>(h3, A4, 16777216L, 256, 4096);
  conv_mfma<3,3,0,3><<<dim3(64,4,16), 256, 0, stream>>>(
      A4, 16777216L, e4w, 589824L, eb4, z,
      256, 64, 64, 256, 8, 1, 1, 0L, 1048576L, 4096L, 64L, 1L);

  // ---------------- VQ ----------------
  transpose_zt<<<dim3(128,8,16), 256, 0, stream>>>(z, zt, res);
  for (int l = 0; l < 4; ++l)
    vq_level<<<1024, 256, 0, stream>>>(cbooks + (long)l*262144, cbn + l*1024,
                                       res, o_idx + l*4096, o_loss + l);
  make_quantized<<<dim3(128,8,16), 256, 0, stream>>>(zt, res, o_q);

  // ---------------- decoder ----------------
  to_nhwc_bf16<2><<<dim3(64,8,16), 256, 0, stream>>>(o_q, D1, 16777216L, 256, 4096);
  conv_mfma<3,3,1,2><<<dim3(64,2,16), 256, 0, stream>>>(
      D1, 16777216L, d1w, 294912L, db1, d1,
      256, 64, 64, 128, 8, 1, 1, 0L, 524288L, 4096L, 64L, 1L);

  to_nhwc_bf16<2><<<dim3(64,4,16), 256, 0, stream>>>(d1, D2, 8388608L, 128, 4096);
  for (int p = 0; p < 4; ++p) {
    int py = p >> 1, px = p & 1;
    conv_mfma<2,2,1,2><<<dim3(64,1,16), 256, 0, stream>>>(
        D2, 8388608L, t2w + p*65536, 32768L, db2, d2,
        128, 64, 64, 64, 8, 1-py, 1-px,
        (long)(py*128 + px), 1048576L, 16384L, 256L, 2L);
  }

  to_nhwc_bf16<2><<<dim3(256,2,16), 256, 0, stream>>>(d2, D3, 16777216L, 64, 16384);
  for (int p = 0; p < 4; ++p) {
    int py = p >> 1, px = p & 1;
    conv_mfma<2,2,1,2><<<dim3(256,1,16), 256, 0, stream>>>(
        D3, 16777216L, t3w + p*32768, 16384L, db3, d3,
        64, 128, 128, 64, 16, 1-py, 1-px,
        (long)(py*256 + px), 4194304L, 65536L, 512L, 2L);
  }

  for (int p = 0; p < 4; ++p) {
    int py = p >> 1, px = p & 1;
    conv_tiled<4,16,16,2,2,1,2><<<dim3(256,1,16), 256, 0, stream>>>(
        d3, wp4 + p*768, db4, o_recon, 16, 64, 256, 256, 3, 16, 1-py, 1-px,
        (long)(py*512 + px), 786432L, 262144L, 1024L, 2L);
  }
  (void)in_sizes; (void)n_in; (void)out_size; (void)ws_size;
}